// Round 6
// baseline (1877.750 us; speedup 1.0000x reference)
//
#include <hip/hip_runtime.h>

// ---------------------------------------------------------------------------
// SequencePredictorRecurrentTransformer on MI355X (gfx950)
//
// I/O: fp32 (x int32). Internal: bf16 storage, fp32 accumulation.
// Layout [b][t][d] bt-major. Batch groups of Bg sized to ws_size.
//
// Round-6 changes:
//  * Swapped-operand MFMA epilogues: mfma(B,A) puts reg-index on the N side,
//    so each lane's 4 acc regs = 4 consecutive output columns -> 8B stores
//    (4x fewer store insts), float4 bias loads. Applied to gemm_mx, gemm_sm,
//    attn_chunk_sums, attn_intra.
//  * f2b uses native HW bf16 cvt (1 VALU) instead of manual RNE (~5 VALU).
//  * Residual (h +) fused into Wo/W2 epilogues; LN reads a single stream.
// ---------------------------------------------------------------------------

typedef unsigned short u16;
typedef __bf16 bf16x8 __attribute__((ext_vector_type(8)));
typedef float f32x4 __attribute__((ext_vector_type(4)));

#define T_SEQ 2048
#define BATCH 32
#define NHEADS 8
#define CT 64
#define NCHUNK 32             // T/CT

__device__ __forceinline__ float b2f(u16 u) {
    union { unsigned int i; float f; } v; v.i = ((unsigned int)u) << 16; return v.f;
}
__device__ __forceinline__ u16 f2b(float f) {
    union { __bf16 b; u16 u; } v; v.b = (__bf16)f; return v.u;   // HW cvt, RNE
}

__device__ __forceinline__ void gl_lds16(const u16* g, u16* l) {
    __builtin_amdgcn_global_load_lds(
        (const __attribute__((address_space(1))) void*)g,
        (__attribute__((address_space(3))) void*)l,
        16, 0, 0);
}

// ---------------------------------------------------------------------------
// m97-structure GEMM: C[M,N] = act(A[M,K] @ BT[N,K]^T + bias[N] [+ R])
// BM=BN=128, BK=64, 4 waves. XOR-swizzled global_load_lds staging.
// Swapped mfma: out_row = lane&15 side, out_col = reg side (8B stores).
// ACT: 0=none, 1=relu, 2=phi(elu+1) where col < act_split.
// ---------------------------------------------------------------------------
template<int ACT, bool RES>
__global__ __launch_bounds__(256) void gemm_mx(
    const u16* __restrict__ A, const u16* __restrict__ BT,
    const float* __restrict__ bias, const u16* __restrict__ R,
    u16* __restrict__ C,
    int M, int N, int K, int act_split, int nbn, int GM)
{
    __shared__ __align__(16) u16 As[128 * 64];
    __shared__ __align__(16) u16 Bs[128 * 64];

    const int bid = blockIdx.x;
    const int gsz = GM * nbn;
    const int grp = bid / gsz, rm = bid % gsz;
    const int bm = (grp * GM + rm % GM) * 128;
    const int bn = (rm / GM) * 128;

    const int tid = threadIdx.x;
    const int lane = tid & 63;
    const int w = tid >> 6;
    const int lrow = lane & 15, quad = lane >> 4;
    const int wrow = (w >> 1) * 64, wcol = (w & 1) * 64;
    const int sr = lane >> 3;
    const int sg = lane & 7;

    f32x4 acc[4][4] = {};

    for (int k0 = 0; k0 < K; k0 += 64) {
        #pragma unroll
        for (int ch4 = 0; ch4 < 4; ch4++) {
            const int chunk = w * 4 + ch4;
            const int r = chunk * 8 + sr;
            const int gs = sg ^ (r & 7);
            gl_lds16(A  + (size_t)(bm + r) * K + k0 + gs * 8, As + chunk * 512);
            gl_lds16(BT + (size_t)(bn + r) * K + k0 + gs * 8, Bs + chunk * 512);
        }
        __syncthreads();
        #pragma unroll
        for (int half = 0; half < 2; half++) {
            bf16x8 af[4], bfv[4];
            #pragma unroll
            for (int i = 0; i < 4; i++) {
                const int r = wrow + i * 16 + lrow;
                const int gq = (half * 4 + quad) ^ (r & 7);
                af[i] = *(const bf16x8*)&As[r * 64 + gq * 8];
            }
            #pragma unroll
            for (int j = 0; j < 4; j++) {
                const int r = wcol + j * 16 + lrow;
                const int gq = (half * 4 + quad) ^ (r & 7);
                bfv[j] = *(const bf16x8*)&Bs[r * 64 + gq * 8];
            }
            #pragma unroll
            for (int i = 0; i < 4; i++)
                #pragma unroll
                for (int j = 0; j < 4; j++)
                    acc[i][j] = __builtin_amdgcn_mfma_f32_16x16x32_bf16(
                        bfv[j], af[i], acc[i][j], 0, 0, 0);   // swapped
        }
        __syncthreads();
    }

    // Epilogue: row = M side (lane&15), col = N side (quad*4 + reg).
    #pragma unroll
    for (int i = 0; i < 4; i++) {
        const int row = bm + wrow + i * 16 + lrow;
        #pragma unroll
        for (int j = 0; j < 4; j++) {
            const int col0 = bn + wcol + j * 16 + quad * 4;
            const float4 bb = *(const float4*)&bias[col0];
            float v[4] = { acc[i][j][0] + bb.x, acc[i][j][1] + bb.y,
                           acc[i][j][2] + bb.z, acc[i][j][3] + bb.w };
            if (RES) {
                uint2 rv = *(const uint2*)&R[(size_t)row * N + col0];
                const u16* rp = (const u16*)&rv;
                #pragma unroll
                for (int r = 0; r < 4; r++) v[r] += b2f(rp[r]);
            }
            if (ACT == 1) {
                #pragma unroll
                for (int r = 0; r < 4; r++) v[r] = fmaxf(v[r], 0.f);
            }
            if (ACT == 2) {
                if (col0 < act_split) {
                    #pragma unroll
                    for (int r = 0; r < 4; r++)
                        v[r] = (v[r] > 0.f) ? (v[r] + 1.f) : __expf(v[r]);
                }
            }
            union { u16 q[4]; uint2 d; } pk;
            #pragma unroll
            for (int r = 0; r < 4; r++) pk.q[r] = f2b(v[r]);
            *(uint2*)&C[(size_t)row * N + col0] = pk.d;
        }
    }
}

// ---------------------------------------------------------------------------
// Small-N GEMM (final projection, N=64): fp32 out, swapped epilogue (16B st).
// ---------------------------------------------------------------------------
template<int BM, int BN, int WM, int WN>
__global__ __launch_bounds__(WM*WN*64) void gemm_sm(
    const u16* __restrict__ A, const u16* __restrict__ BT,
    const float* __restrict__ bias, float* __restrict__ C,
    int M, int N, int K)
{
    constexpr int BK = 32;
    constexpr int LDT = BK + 8;
    constexpr int NTHR = WM * WN * 64;
    __shared__ __align__(16) u16 As[BM * LDT];
    __shared__ __align__(16) u16 Bs[BN * LDT];

    const int tid = threadIdx.x;
    const int bm = blockIdx.y * BM;
    const int bn = blockIdx.x * BN;
    const int lane = tid & 63;
    const int wid = tid >> 6;
    const int wrow = (wid / WN) * (BM / WM);
    const int wcol = (wid % WN) * (BN / WN);
    constexpr int FM = BM / WM / 16;
    constexpr int FN = BN / WN / 16;
    const int lrow = lane & 15;
    const int lk = (lane >> 4) * 8;

    f32x4 acc[FM][FN] = {};

    for (int k0 = 0; k0 < K; k0 += BK) {
        #pragma unroll
        for (int g0 = 0; g0 < BM * 4; g0 += NTHR) {
            int g = g0 + tid;
            int row = g >> 2, kk = (g & 3) * 8;
            *(uint4*)&As[row * LDT + kk] =
                *(const uint4*)&A[(size_t)(bm + row) * K + k0 + kk];
        }
        #pragma unroll
        for (int g0 = 0; g0 < BN * 4; g0 += NTHR) {
            int g = g0 + tid;
            int row = g >> 2, kk = (g & 3) * 8;
            *(uint4*)&Bs[row * LDT + kk] =
                *(const uint4*)&BT[(size_t)(bn + row) * K + k0 + kk];
        }
        __syncthreads();
        bf16x8 af[FM], bfv[FN];
        #pragma unroll
        for (int i = 0; i < FM; i++)
            af[i] = *(const bf16x8*)&As[(wrow + i * 16 + lrow) * LDT + lk];
        #pragma unroll
        for (int j = 0; j < FN; j++)
            bfv[j] = *(const bf16x8*)&Bs[(wcol + j * 16 + lrow) * LDT + lk];
        #pragma unroll
        for (int i = 0; i < FM; i++)
            #pragma unroll
            for (int j = 0; j < FN; j++)
                acc[i][j] = __builtin_amdgcn_mfma_f32_16x16x32_bf16(
                    bfv[j], af[i], acc[i][j], 0, 0, 0);   // swapped
        __syncthreads();
    }

    #pragma unroll
    for (int i = 0; i < FM; i++) {
        const int row = bm + wrow + i * 16 + lrow;
        #pragma unroll
        for (int j = 0; j < FN; j++) {
            const int col0 = bn + wcol + j * 16 + (lane >> 4) * 4;
            const float4 bb = *(const float4*)&bias[col0];
            float4 o = { acc[i][j][0] + bb.x, acc[i][j][1] + bb.y,
                         acc[i][j][2] + bb.z, acc[i][j][3] + bb.w };
            *(float4*)&C[(size_t)row * N + col0] = o;
        }
    }
}

// ---------------------------------------------------------------------------
__global__ __launch_bounds__(256) void transpose_w(
    const float* __restrict__ src, u16* __restrict__ dst, int K, int N)
{
    __shared__ float tile[32][33];
    int bx = blockIdx.x, by = blockIdx.y;
    int tx = threadIdx.x & 31, ty = threadIdx.x >> 5;
    #pragma unroll
    for (int yy = 0; yy < 4; yy++) {
        int k = by * 32 + ty + yy * 8;
        tile[ty + yy * 8][tx] = src[(size_t)k * N + bx * 32 + tx];
    }
    __syncthreads();
    #pragma unroll
    for (int yy = 0; yy < 4; yy++) {
        int n = bx * 32 + ty + yy * 8;
        dst[(size_t)n * K + by * 32 + tx] = f2b(tile[tx][ty + yy * 8]);
    }
}

__global__ __launch_bounds__(256) void concat_bias(
    const float* __restrict__ bq, const float* __restrict__ bk,
    const float* __restrict__ bv, float* __restrict__ dst)
{
    int id = blockIdx.x * 256 + threadIdx.x;
    if (id >= 3072) return;
    int l = id / 1536, i = id % 1536;
    float v = (i < 512) ? bq[l * 512 + i]
            : (i < 1024) ? bk[l * 512 + i - 512]
                         : bv[l * 512 + i - 1024];
    dst[id] = v;
}

// ---------------------------------------------------------------------------
__global__ __launch_bounds__(256) void embed_kernel(
    const int* __restrict__ x, const float* __restrict__ E, u16* __restrict__ h,
    int b0)
{
    int e = blockIdx.x * 256 + threadIdx.x;
    int r = e >> 9;
    int c = e & 511;
    int t = r & (T_SEQ - 1);
    int b = b0 + (r >> 11);
    float v;
    if (c < 256) {
        v = E[x[t * BATCH + b] * 256 + c];
    } else {
        int j = c - 256;
        int i = j >> 1;
        float div = expf(-(float)(2 * i) * (9.210340371976184f / 256.f));
        float arg = (float)t * div;
        v = (j & 1) ? cosf(arg) : sinf(arg);
    }
    h[e] = f2b(v);
}

// ---------------------------------------------------------------------------
// Phase A (MFMA, swapped): S'_c[m][d] = sum_t V[t][m]*K[t][d] -> bf16 8B st.
// ---------------------------------------------------------------------------
__global__ __launch_bounds__(256) void attn_chunk_sums(
    const u16* __restrict__ qkv, u16* __restrict__ S, float* __restrict__ Z,
    int BHg)
{
    __shared__ __align__(16) u16 Kt[64 * 72], Vt[64 * 72];   // [d][t], [m][t]
    int bid = blockIdx.x;
    int bh = bid % BHg, c = bid / BHg;
    int bl = bh >> 3, hh = bh & 7;
    for (int idx = threadIdx.x; idx < 4096; idx += 256) {
        int t = idx >> 6, d = idx & 63;
        size_t r = ((size_t)(bl * T_SEQ + c * 64 + t)) * 1536 + hh * 64 + d;
        Kt[d * 72 + t] = qkv[r + 512];
        Vt[d * 72 + t] = qkv[r + 1024];
    }
    __syncthreads();
    int lane = threadIdx.x & 63;
    int w = threadIdx.x >> 6;
    int lrow = lane & 15, quad = lane >> 4;
    int m0 = w * 16;
    f32x4 acc[4] = {};
    #pragma unroll
    for (int k0 = 0; k0 < 64; k0 += 32) {
        bf16x8 af = *(const bf16x8*)&Vt[(m0 + lrow) * 72 + k0 + quad * 8];
        #pragma unroll
        for (int jt = 0; jt < 4; jt++) {
            bf16x8 bf = *(const bf16x8*)&Kt[(jt * 16 + lrow) * 72 + k0 + quad * 8];
            acc[jt] = __builtin_amdgcn_mfma_f32_16x16x32_bf16(bf, af, acc[jt], 0, 0, 0);
        }
    }
    size_t base = ((size_t)c * BHg + bh) * 4096;
    const int m = m0 + lrow;
    #pragma unroll
    for (int jt = 0; jt < 4; jt++) {
        const int d0 = jt * 16 + quad * 4;
        union { u16 q[4]; uint2 u; } pk;
        #pragma unroll
        for (int r = 0; r < 4; r++) pk.q[r] = f2b(acc[jt][r]);
        *(uint2*)&S[base + m * 64 + d0] = pk.u;
    }
    if (threadIdx.x < 64) {
        float z = 0.f;
        #pragma unroll
        for (int t8 = 0; t8 < 64; t8 += 8) {
            bf16x8 kk = *(const bf16x8*)&Kt[threadIdx.x * 72 + t8];
            #pragma unroll
            for (int u = 0; u < 8; u++) z += (float)kk[u];
        }
        Z[((size_t)c * BHg + bh) * 64 + threadIdx.x] = z;
    }
}

// ---------------------------------------------------------------------------
// Phase B: exclusive prefix over chunks; register scan, loads all in flight.
// ---------------------------------------------------------------------------
__global__ __launch_bounds__(256) void attn_prefix(
    u16* __restrict__ S, float* __restrict__ Z, int BHg)
{
    int gid = blockIdx.x * 256 + threadIdx.x;   // < BHg*4096
    int bh = gid >> 12, e = gid & 4095;
    size_t stride = (size_t)BHg * 4096;
    size_t base = (size_t)bh * 4096 + e;
    float v[NCHUNK];
    #pragma unroll
    for (int c = 0; c < NCHUNK; c++) v[c] = b2f(S[base + c * stride]);
    float run = 0.f;
    #pragma unroll
    for (int c = 0; c < NCHUNK; c++) {
        float t = v[c]; S[base + c * stride] = f2b(run); run += t;
    }
    if (gid < BHg * 64) {
        size_t zb = (size_t)gid;
        size_t zs = (size_t)BHg * 64;
        float zv[NCHUNK];
        #pragma unroll
        for (int c = 0; c < NCHUNK; c++) zv[c] = Z[zb + c * zs];
        float zr = 0.f;
        #pragma unroll
        for (int c = 0; c < NCHUNK; c++) {
            float t = zv[c]; Z[zb + c * zs] = zr; zr += t;
        }
    }
}

// ---------------------------------------------------------------------------
// Phase C (MFMA): P=QK^T masked; O=(P@V + Q@S')/den. Second stage swapped:
// out row = lane&15 side, head-col = reg side -> 8B stores.
// ---------------------------------------------------------------------------
__global__ __launch_bounds__(256) void attn_intra(
    const u16* __restrict__ qkv, const u16* __restrict__ Sp,
    const float* __restrict__ Zp, u16* __restrict__ out, int BHg)
{
    __shared__ __align__(16) u16 Qs[64 * 72], Ks[64 * 72], Vt[64 * 72],
                                 Ps[64 * 72], Ssh[64 * 72];
    __shared__ float Zsh[64], den2sh[64], den1sh[64];
    int bid = blockIdx.x;
    int bh = bid % BHg, c = bid / BHg;
    int bl = bh >> 3, hh = bh & 7;
    size_t sbase = ((size_t)c * BHg + bh) * 4096;
    for (int idx = threadIdx.x; idx < 4096; idx += 256) {
        int t = idx >> 6, d = idx & 63;
        size_t r = ((size_t)(bl * T_SEQ + c * 64 + t)) * 1536 + hh * 64 + d;
        Qs[t * 72 + d] = qkv[r];
        Ks[t * 72 + d] = qkv[r + 512];
        Vt[d * 72 + t] = qkv[r + 1024];         // [m][t]
        Ssh[t * 72 + d] = Sp[sbase + idx];      // [m][d]
    }
    if (threadIdx.x < 64)
        Zsh[threadIdx.x] = Zp[((size_t)c * BHg + bh) * 64 + threadIdx.x];
    __syncthreads();

    if (threadIdx.x < 64) {
        float s = 0.f;
        #pragma unroll
        for (int d8 = 0; d8 < 64; d8 += 8) {
            bf16x8 qq = *(const bf16x8*)&Qs[threadIdx.x * 72 + d8];
            #pragma unroll
            for (int u = 0; u < 8; u++) s += (float)qq[u] * Zsh[d8 + u];
        }
        den2sh[threadIdx.x] = s;
    }

    int lane = threadIdx.x & 63;
    int w = threadIdx.x >> 6;
    int lrow = lane & 15, quad = lane >> 4;
    int i0 = w * 16;

    // P = Q @ K^T (original orientation: row = i via reg)
    f32x4 accp[4] = {};
    #pragma unroll
    for (int k0 = 0; k0 < 64; k0 += 32) {
        bf16x8 af = *(const bf16x8*)&Qs[(i0 + lrow) * 72 + k0 + quad * 8];
        #pragma unroll
        for (int jt = 0; jt < 4; jt++) {
            bf16x8 bf = *(const bf16x8*)&Ks[(jt * 16 + lrow) * 72 + k0 + quad * 8];
            accp[jt] = __builtin_amdgcn_mfma_f32_16x16x32_bf16(af, bf, accp[jt], 0, 0, 0);
        }
    }
    #pragma unroll
    for (int r = 0; r < 4; r++) {
        int row = i0 + quad * 4 + r;
        float d1 = 0.f;
        #pragma unroll
        for (int jt = 0; jt < 4; jt++) {
            int col = jt * 16 + lrow;
            float pv = (col <= row) ? accp[jt][r] : 0.f;
            d1 += pv;
            Ps[row * 72 + col] = f2b(pv);
        }
        #pragma unroll
        for (int off = 1; off < 16; off <<= 1)
            d1 += __shfl_xor(d1, off, 64);
        if (lrow == 0) den1sh[row] = d1;
    }
    __syncthreads();

    // O = Ps @ V + Q @ S'  (swapped: first operand = m side)
    f32x4 acco[4] = {};
    #pragma unroll
    for (int k0 = 0; k0 < 64; k0 += 32) {
        bf16x8 ps = *(const bf16x8*)&Ps[(i0 + lrow) * 72 + k0 + quad * 8];
        #pragma unroll
        for (int jt = 0; jt < 4; jt++) {
            bf16x8 vf = *(const bf16x8*)&Vt[(jt * 16 + lrow) * 72 + k0 + quad * 8];
            acco[jt] = __builtin_amdgcn_mfma_f32_16x16x32_bf16(vf, ps, acco[jt], 0, 0, 0);
        }
    }
    #pragma unroll
    for (int k0 = 0; k0 < 64; k0 += 32) {
        bf16x8 qf = *(const bf16x8*)&Qs[(i0 + lrow) * 72 + k0 + quad * 8];
        #pragma unroll
        for (int jt = 0; jt < 4; jt++) {
            bf16x8 sf = *(const bf16x8*)&Ssh[(jt * 16 + lrow) * 72 + k0 + quad * 8];
            acco[jt] = __builtin_amdgcn_mfma_f32_16x16x32_bf16(sf, qf, acco[jt], 0, 0, 0);
        }
    }
    const int i = i0 + lrow;
    const float inv = 1.f / (den1sh[i] + den2sh[i] + 1e-6f);
    size_t orow = ((size_t)(bl * T_SEQ + c * 64 + i)) * 512 + hh * 64;
    #pragma unroll
    for (int jt = 0; jt < 4; jt++) {
        const int m0 = jt * 16 + quad * 4;
        union { u16 q[4]; uint2 u; } pk;
        #pragma unroll
        for (int r = 0; r < 4; r++) pk.q[r] = f2b(acco[jt][r] * inv);
        *(uint2*)&out[orow + m0] = pk.u;
    }
}

// ---------------------------------------------------------------------------
// LayerNorm (single input stream; residual pre-added in GEMM epilogue):
// out = LN(s) * g + be
// ---------------------------------------------------------------------------
__global__ __launch_bounds__(256) void ln_kernel(
    const u16* __restrict__ s_in,
    const float* __restrict__ g, const float* __restrict__ be, u16* __restrict__ out)
{
    int row = blockIdx.x * 4 + (threadIdx.x >> 6);
    int lane = threadIdx.x & 63;
    size_t base = (size_t)row * 512 + lane * 8;
    uint4 hv = *(const uint4*)&s_in[base];
    const u16* hp = (const u16*)&hv;
    float x[8]; float s = 0.f;
    #pragma unroll
    for (int i = 0; i < 8; i++) { x[i] = b2f(hp[i]); s += x[i]; }
    #pragma unroll
    for (int off = 32; off > 0; off >>= 1) s += __shfl_xor(s, off, 64);
    float m = s * (1.f / 512.f);
    float vs = 0.f;
    #pragma unroll
    for (int i = 0; i < 8; i++) { float t = x[i] - m; vs += t * t; }
    #pragma unroll
    for (int off = 32; off > 0; off >>= 1) vs += __shfl_xor(vs, off, 64);
    float rstd = rsqrtf(vs * (1.f / 512.f) + 1e-5f);
    union { u16 u[8]; uint4 v; } o;
    #pragma unroll
    for (int i = 0; i < 8; i++)
        o.u[i] = f2b((x[i] - m) * rstd * g[lane * 8 + i] + be[lane * 8 + i]);
    *(uint4*)&out[base] = o.v;
}

// ---------------------------------------------------------------------------
extern "C" void kernel_launch(void* const* d_in, const int* in_sizes, int n_in,
                              void* d_out, int out_size, void* d_ws, size_t ws_size,
                              hipStream_t stream)
{
    const int*   x  = (const int*)d_in[0];
    const float* E  = (const float*)d_in[1];
    const float* Wq = (const float*)d_in[2];
    const float* bq = (const float*)d_in[3];
    const float* Wk = (const float*)d_in[4];
    const float* bk = (const float*)d_in[5];
    const float* Wv = (const float*)d_in[6];
    const float* bv = (const float*)d_in[7];
    const float* Wo = (const float*)d_in[8];
    const float* bo = (const float*)d_in[9];
    const float* g1 = (const float*)d_in[10];
    const float* be1= (const float*)d_in[11];
    const float* W1 = (const float*)d_in[12];
    const float* b1 = (const float*)d_in[13];
    const float* W2 = (const float*)d_in[14];
    const float* b2 = (const float*)d_in[15];
    const float* g2 = (const float*)d_in[16];
    const float* be2= (const float*)d_in[17];
    const float* Wp = (const float*)d_in[18];
    const float* bp = (const float*)d_in[19];

    // --- fixed region: bf16 transposed weights + fp32 qkv bias (12.08 MiB) ---
    char* p = (char*)d_ws;
    u16* qkvT = (u16*)p; p += (size_t)2 * 1536 * 512 * 2;
    u16* woT  = (u16*)p; p += (size_t)2 * 512 * 512 * 2;
    u16* w1T  = (u16*)p; p += (size_t)2 * 2048 * 512 * 2;
    u16* w2T  = (u16*)p; p += (size_t)2 * 512 * 2048 * 2;
    u16* wpT  = (u16*)p; p += (size_t)64 * 512 * 2;
    float* bqkv = (float*)p; p += (size_t)16384;
    size_t fixed = (size_t)(p - (char*)d_ws);

    // --- adaptive batch group: Bg * 12.65 MiB ---
    const size_t perB = 12648448ULL;
    int Bg = 32;
    while (Bg > 1 && fixed + (size_t)Bg * perB > ws_size) Bg >>= 1;
    const int rows = Bg * T_SEQ;
    const int BHg = Bg * NHEADS;
    const int nbm = rows / 128;

    u16* h      = (u16*)p; p += (size_t)rows * 512 * 2;
    u16* qkvBig = (u16*)p; p += (size_t)rows * 2048 * 2;
    u16* am     = (u16*)p; p += (size_t)rows * 512 * 2;
    float* Z    = (float*)p; p += (size_t)BHg * NCHUNK * 64 * 4;
    u16* qkv = qkvBig;                        // rows x 1536 during attention
    u16* Sb  = qkvBig + (size_t)rows * 1536;  // bf16 S' tail
    u16* ff1 = qkvBig;                        // rows x 2048 during FF
    u16* o_  = qkvBig;                        // rows x 512 Wo output (h+attn)

    dim3 blk(256);

    for (int l = 0; l < 2; l++) {
        transpose_w<<<dim3(16, 16), blk, 0, stream>>>(Wq + (size_t)l * 262144, qkvT + (size_t)l * 786432,          512, 512);
        transpose_w<<<dim3(16, 16), blk, 0, stream>>>(Wk + (size_t)l * 262144, qkvT + (size_t)l * 786432 + 262144, 512, 512);
        transpose_w<<<dim3(16, 16), blk, 0, stream>>>(Wv + (size_t)l * 262144, qkvT + (size_t)l * 786432 + 524288, 512, 512);
        transpose_w<<<dim3(16, 16), blk, 0, stream>>>(Wo + (size_t)l * 262144, woT + (size_t)l * 262144,           512, 512);
        transpose_w<<<dim3(64, 16), blk, 0, stream>>>(W1 + (size_t)l * 1048576, w1T + (size_t)l * 1048576,         512, 2048);
        transpose_w<<<dim3(16, 64), blk, 0, stream>>>(W2 + (size_t)l * 1048576, w2T + (size_t)l * 1048576,         2048, 512);
    }
    transpose_w<<<dim3(2, 16), blk, 0, stream>>>(Wp, wpT, 512, 64);
    concat_bias<<<12, blk, 0, stream>>>(bq, bk, bv, bqkv);

    for (int b0 = 0; b0 < BATCH; b0 += Bg) {
        embed_kernel<<<rows * 2, blk, 0, stream>>>(x, E, h, b0);

        for (int l = 0; l < 2; l++) {
            gemm_mx<2, false><<<dim3(nbm * 12), blk, 0, stream>>>(
                h, qkvT + (size_t)l * 786432, bqkv + l * 1536, nullptr, qkv,
                rows, 1536, 512, 1024, 12, 8);
            attn_chunk_sums<<<NCHUNK * BHg, blk, 0, stream>>>(qkv, Sb, Z, BHg);
            attn_prefix<<<BHg * 16, blk, 0, stream>>>(Sb, Z, BHg);
            attn_intra<<<NCHUNK * BHg, blk, 0, stream>>>(qkv, Sb, Z, am, BHg);
            gemm_mx<0, true><<<dim3(nbm * 4), blk, 0, stream>>>(
                am, woT + (size_t)l * 262144, bo + l * 512, h, o_,
                rows, 512, 512, 0, 4, 8);
            ln_kernel<<<rows / 4, blk, 0, stream>>>(o_, g1 + l * 512, be1 + l * 512, h);
            gemm_mx<1, false><<<dim3(nbm * 16), blk, 0, stream>>>(
                h, w1T + (size_t)l * 1048576, b1 + l * 2048, nullptr, ff1,
                rows, 2048, 512, 0, 16, 8);
            gemm_mx<0, true><<<dim3(nbm * 4), blk, 0, stream>>>(
                ff1, w2T + (size_t)l * 1048576, b2 + l * 512, h, am,
                rows, 512, 2048, 0, 4, 8);
            ln_kernel<<<rows / 4, blk, 0, stream>>>(am, g2 + l * 512, be2 + l * 512, h);
        }

        gemm_sm<64, 64, 2, 2><<<dim3(1, rows / 64), blk, 0, stream>>>(
            h, wpT, bp, (float*)d_out + (size_t)b0 * T_SEQ * 64, rows, 64, 512);
    }

    (void)in_sizes; (void)n_in; (void)out_size; (void)ws_size;
}

// Round 7
// 1708.723 us; speedup vs baseline: 1.0989x; 1.0989x over previous
//
#include <hip/hip_runtime.h>

// ---------------------------------------------------------------------------
// SequencePredictorRecurrentTransformer on MI355X (gfx950)
//
// I/O: fp32 (x int32). Internal: bf16 storage, fp32 accumulation.
// Layout [b][t][d] bt-major. Batch groups of Bg sized to ws_size.
//
// Round-7: revert gemm_mx to the round-5 (unswapped, VGPR-88) body --
// round-6's swapped epilogue raised VGPR 88->108 (waves/SIMD 5->4) and
// regressed 15%. Keep: HW f2b cast, residual fusion in Wo/W2 epilogues
// (RES), single-stream LN, round-6 attention kernels.
// ---------------------------------------------------------------------------

typedef unsigned short u16;
typedef __bf16 bf16x8 __attribute__((ext_vector_type(8)));
typedef float f32x4 __attribute__((ext_vector_type(4)));

#define T_SEQ 2048
#define BATCH 32
#define NHEADS 8
#define CT 64
#define NCHUNK 32             // T/CT

__device__ __forceinline__ float b2f(u16 u) {
    union { unsigned int i; float f; } v; v.i = ((unsigned int)u) << 16; return v.f;
}
__device__ __forceinline__ u16 f2b(float f) {
    union { __bf16 b; u16 u; } v; v.b = (__bf16)f; return v.u;   // HW cvt, RNE
}

__device__ __forceinline__ void gl_lds16(const u16* g, u16* l) {
    __builtin_amdgcn_global_load_lds(
        (const __attribute__((address_space(1))) void*)g,
        (__attribute__((address_space(3))) void*)l,
        16, 0, 0);
}

// ---------------------------------------------------------------------------
// m97-structure GEMM (round-5 body): C[M,N] = act(A@BT^T + bias [+ R])
// BM=BN=128, BK=64, 4 waves x 64x64 acc. XOR-swizzled global_load_lds.
// ACT: 0=none, 1=relu, 2=phi(elu+1) where col < act_split.
// ---------------------------------------------------------------------------
template<int ACT, bool RES>
__global__ __launch_bounds__(256) void gemm_mx(
    const u16* __restrict__ A, const u16* __restrict__ BT,
    const float* __restrict__ bias, const u16* __restrict__ R,
    u16* __restrict__ C,
    int M, int N, int K, int act_split, int nbn, int GM)
{
    __shared__ __align__(16) u16 As[128 * 64];
    __shared__ __align__(16) u16 Bs[128 * 64];

    const int bid = blockIdx.x;
    const int gsz = GM * nbn;
    const int grp = bid / gsz, rm = bid % gsz;
    const int bm = (grp * GM + rm % GM) * 128;
    const int bn = (rm / GM) * 128;

    const int tid = threadIdx.x;
    const int lane = tid & 63;
    const int w = tid >> 6;
    const int lrow = lane & 15, quad = lane >> 4;
    const int wrow = (w >> 1) * 64, wcol = (w & 1) * 64;
    const int sr = lane >> 3;          // staging: row within 8-row chunk
    const int sg = lane & 7;           // staging: granule slot in row

    f32x4 acc[4][4] = {};

    for (int k0 = 0; k0 < K; k0 += 64) {
        #pragma unroll
        for (int ch4 = 0; ch4 < 4; ch4++) {
            const int chunk = w * 4 + ch4;        // 0..15 (8 rows each)
            const int r = chunk * 8 + sr;         // 0..127
            const int gs = sg ^ (r & 7);          // swizzled source granule
            gl_lds16(A  + (size_t)(bm + r) * K + k0 + gs * 8, As + chunk * 512);
            gl_lds16(BT + (size_t)(bn + r) * K + k0 + gs * 8, Bs + chunk * 512);
        }
        __syncthreads();
        #pragma unroll
        for (int half = 0; half < 2; half++) {
            bf16x8 af[4], bfv[4];
            #pragma unroll
            for (int i = 0; i < 4; i++) {
                const int r = wrow + i * 16 + lrow;
                const int gq = (half * 4 + quad) ^ (r & 7);
                af[i] = *(const bf16x8*)&As[r * 64 + gq * 8];
            }
            #pragma unroll
            for (int j = 0; j < 4; j++) {
                const int r = wcol + j * 16 + lrow;
                const int gq = (half * 4 + quad) ^ (r & 7);
                bfv[j] = *(const bf16x8*)&Bs[r * 64 + gq * 8];
            }
            #pragma unroll
            for (int i = 0; i < 4; i++)
                #pragma unroll
                for (int j = 0; j < 4; j++)
                    acc[i][j] = __builtin_amdgcn_mfma_f32_16x16x32_bf16(
                        af[i], bfv[j], acc[i][j], 0, 0, 0);
        }
        __syncthreads();
    }

    // Epilogue (round-5 layout). D: col = lane&15, row = quad*4 + r.
    #pragma unroll
    for (int i = 0; i < 4; i++) {
        const int row0 = bm + wrow + i * 16 + quad * 4;
        #pragma unroll
        for (int j = 0; j < 4; j++) {
            const int col = bn + wcol + j * 16 + lrow;
            const float bb = bias[col];
            #pragma unroll
            for (int r = 0; r < 4; r++) {
                float v = acc[i][j][r] + bb;
                if (RES) v += b2f(R[(size_t)(row0 + r) * N + col]);
                if (ACT == 1) v = fmaxf(v, 0.f);
                if (ACT == 2) { if (col < act_split) v = (v > 0.f) ? (v + 1.f) : __expf(v); }
                C[(size_t)(row0 + r) * N + col] = f2b(v);
            }
        }
    }
}

// ---------------------------------------------------------------------------
// Small-N GEMM (final projection, N=64): fp32 out, swapped epilogue (16B st).
// ---------------------------------------------------------------------------
template<int BM, int BN, int WM, int WN>
__global__ __launch_bounds__(WM*WN*64) void gemm_sm(
    const u16* __restrict__ A, const u16* __restrict__ BT,
    const float* __restrict__ bias, float* __restrict__ C,
    int M, int N, int K)
{
    constexpr int BK = 32;
    constexpr int LDT = BK + 8;
    constexpr int NTHR = WM * WN * 64;
    __shared__ __align__(16) u16 As[BM * LDT];
    __shared__ __align__(16) u16 Bs[BN * LDT];

    const int tid = threadIdx.x;
    const int bm = blockIdx.y * BM;
    const int bn = blockIdx.x * BN;
    const int lane = tid & 63;
    const int wid = tid >> 6;
    const int wrow = (wid / WN) * (BM / WM);
    const int wcol = (wid % WN) * (BN / WN);
    constexpr int FM = BM / WM / 16;
    constexpr int FN = BN / WN / 16;
    const int lrow = lane & 15;
    const int lk = (lane >> 4) * 8;

    f32x4 acc[FM][FN] = {};

    for (int k0 = 0; k0 < K; k0 += BK) {
        #pragma unroll
        for (int g0 = 0; g0 < BM * 4; g0 += NTHR) {
            int g = g0 + tid;
            int row = g >> 2, kk = (g & 3) * 8;
            *(uint4*)&As[row * LDT + kk] =
                *(const uint4*)&A[(size_t)(bm + row) * K + k0 + kk];
        }
        #pragma unroll
        for (int g0 = 0; g0 < BN * 4; g0 += NTHR) {
            int g = g0 + tid;
            int row = g >> 2, kk = (g & 3) * 8;
            *(uint4*)&Bs[row * LDT + kk] =
                *(const uint4*)&BT[(size_t)(bn + row) * K + k0 + kk];
        }
        __syncthreads();
        bf16x8 af[FM], bfv[FN];
        #pragma unroll
        for (int i = 0; i < FM; i++)
            af[i] = *(const bf16x8*)&As[(wrow + i * 16 + lrow) * LDT + lk];
        #pragma unroll
        for (int j = 0; j < FN; j++)
            bfv[j] = *(const bf16x8*)&Bs[(wcol + j * 16 + lrow) * LDT + lk];
        #pragma unroll
        for (int i = 0; i < FM; i++)
            #pragma unroll
            for (int j = 0; j < FN; j++)
                acc[i][j] = __builtin_amdgcn_mfma_f32_16x16x32_bf16(
                    bfv[j], af[i], acc[i][j], 0, 0, 0);   // swapped
        __syncthreads();
    }

    #pragma unroll
    for (int i = 0; i < FM; i++) {
        const int row = bm + wrow + i * 16 + lrow;
        #pragma unroll
        for (int j = 0; j < FN; j++) {
            const int col0 = bn + wcol + j * 16 + (lane >> 4) * 4;
            const float4 bb = *(const float4*)&bias[col0];
            float4 o = { acc[i][j][0] + bb.x, acc[i][j][1] + bb.y,
                         acc[i][j][2] + bb.z, acc[i][j][3] + bb.w };
            *(float4*)&C[(size_t)row * N + col0] = o;
        }
    }
}

// ---------------------------------------------------------------------------
__global__ __launch_bounds__(256) void transpose_w(
    const float* __restrict__ src, u16* __restrict__ dst, int K, int N)
{
    __shared__ float tile[32][33];
    int bx = blockIdx.x, by = blockIdx.y;
    int tx = threadIdx.x & 31, ty = threadIdx.x >> 5;
    #pragma unroll
    for (int yy = 0; yy < 4; yy++) {
        int k = by * 32 + ty + yy * 8;
        tile[ty + yy * 8][tx] = src[(size_t)k * N + bx * 32 + tx];
    }
    __syncthreads();
    #pragma unroll
    for (int yy = 0; yy < 4; yy++) {
        int n = bx * 32 + ty + yy * 8;
        dst[(size_t)n * K + by * 32 + tx] = f2b(tile[tx][ty + yy * 8]);
    }
}

__global__ __launch_bounds__(256) void concat_bias(
    const float* __restrict__ bq, const float* __restrict__ bk,
    const float* __restrict__ bv, float* __restrict__ dst)
{
    int id = blockIdx.x * 256 + threadIdx.x;
    if (id >= 3072) return;
    int l = id / 1536, i = id % 1536;
    float v = (i < 512) ? bq[l * 512 + i]
            : (i < 1024) ? bk[l * 512 + i - 512]
                         : bv[l * 512 + i - 1024];
    dst[id] = v;
}

// ---------------------------------------------------------------------------
__global__ __launch_bounds__(256) void embed_kernel(
    const int* __restrict__ x, const float* __restrict__ E, u16* __restrict__ h,
    int b0)
{
    int e = blockIdx.x * 256 + threadIdx.x;
    int r = e >> 9;
    int c = e & 511;
    int t = r & (T_SEQ - 1);
    int b = b0 + (r >> 11);
    float v;
    if (c < 256) {
        v = E[x[t * BATCH + b] * 256 + c];
    } else {
        int j = c - 256;
        int i = j >> 1;
        float div = expf(-(float)(2 * i) * (9.210340371976184f / 256.f));
        float arg = (float)t * div;
        v = (j & 1) ? cosf(arg) : sinf(arg);
    }
    h[e] = f2b(v);
}

// ---------------------------------------------------------------------------
// Phase A (MFMA, swapped): S'_c[m][d] = sum_t V[t][m]*K[t][d] -> bf16 8B st.
// ---------------------------------------------------------------------------
__global__ __launch_bounds__(256) void attn_chunk_sums(
    const u16* __restrict__ qkv, u16* __restrict__ S, float* __restrict__ Z,
    int BHg)
{
    __shared__ __align__(16) u16 Kt[64 * 72], Vt[64 * 72];   // [d][t], [m][t]
    int bid = blockIdx.x;
    int bh = bid % BHg, c = bid / BHg;
    int bl = bh >> 3, hh = bh & 7;
    for (int idx = threadIdx.x; idx < 4096; idx += 256) {
        int t = idx >> 6, d = idx & 63;
        size_t r = ((size_t)(bl * T_SEQ + c * 64 + t)) * 1536 + hh * 64 + d;
        Kt[d * 72 + t] = qkv[r + 512];
        Vt[d * 72 + t] = qkv[r + 1024];
    }
    __syncthreads();
    int lane = threadIdx.x & 63;
    int w = threadIdx.x >> 6;
    int lrow = lane & 15, quad = lane >> 4;
    int m0 = w * 16;
    f32x4 acc[4] = {};
    #pragma unroll
    for (int k0 = 0; k0 < 64; k0 += 32) {
        bf16x8 af = *(const bf16x8*)&Vt[(m0 + lrow) * 72 + k0 + quad * 8];
        #pragma unroll
        for (int jt = 0; jt < 4; jt++) {
            bf16x8 bf = *(const bf16x8*)&Kt[(jt * 16 + lrow) * 72 + k0 + quad * 8];
            acc[jt] = __builtin_amdgcn_mfma_f32_16x16x32_bf16(bf, af, acc[jt], 0, 0, 0);
        }
    }
    size_t base = ((size_t)c * BHg + bh) * 4096;
    const int m = m0 + lrow;
    #pragma unroll
    for (int jt = 0; jt < 4; jt++) {
        const int d0 = jt * 16 + quad * 4;
        union { u16 q[4]; uint2 u; } pk;
        #pragma unroll
        for (int r = 0; r < 4; r++) pk.q[r] = f2b(acc[jt][r]);
        *(uint2*)&S[base + m * 64 + d0] = pk.u;
    }
    if (threadIdx.x < 64) {
        float z = 0.f;
        #pragma unroll
        for (int t8 = 0; t8 < 64; t8 += 8) {
            bf16x8 kk = *(const bf16x8*)&Kt[threadIdx.x * 72 + t8];
            #pragma unroll
            for (int u = 0; u < 8; u++) z += (float)kk[u];
        }
        Z[((size_t)c * BHg + bh) * 64 + threadIdx.x] = z;
    }
}

// ---------------------------------------------------------------------------
// Phase B: exclusive prefix over chunks; register scan, loads all in flight.
// ---------------------------------------------------------------------------
__global__ __launch_bounds__(256) void attn_prefix(
    u16* __restrict__ S, float* __restrict__ Z, int BHg)
{
    int gid = blockIdx.x * 256 + threadIdx.x;   // < BHg*4096
    int bh = gid >> 12, e = gid & 4095;
    size_t stride = (size_t)BHg * 4096;
    size_t base = (size_t)bh * 4096 + e;
    float v[NCHUNK];
    #pragma unroll
    for (int c = 0; c < NCHUNK; c++) v[c] = b2f(S[base + c * stride]);
    float run = 0.f;
    #pragma unroll
    for (int c = 0; c < NCHUNK; c++) {
        float t = v[c]; S[base + c * stride] = f2b(run); run += t;
    }
    if (gid < BHg * 64) {
        size_t zb = (size_t)gid;
        size_t zs = (size_t)BHg * 64;
        float zv[NCHUNK];
        #pragma unroll
        for (int c = 0; c < NCHUNK; c++) zv[c] = Z[zb + c * zs];
        float zr = 0.f;
        #pragma unroll
        for (int c = 0; c < NCHUNK; c++) {
            float t = zv[c]; Z[zb + c * zs] = zr; zr += t;
        }
    }
}

// ---------------------------------------------------------------------------
// Phase C (MFMA): P=QK^T masked; O=(P@V + Q@S')/den. Second stage swapped:
// out row = lane&15 side, head-col = reg side -> 8B stores.
// ---------------------------------------------------------------------------
__global__ __launch_bounds__(256) void attn_intra(
    const u16* __restrict__ qkv, const u16* __restrict__ Sp,
    const float* __restrict__ Zp, u16* __restrict__ out, int BHg)
{
    __shared__ __align__(16) u16 Qs[64 * 72], Ks[64 * 72], Vt[64 * 72],
                                 Ps[64 * 72], Ssh[64 * 72];
    __shared__ float Zsh[64], den2sh[64], den1sh[64];
    int bid = blockIdx.x;
    int bh = bid % BHg, c = bid / BHg;
    int bl = bh >> 3, hh = bh & 7;
    size_t sbase = ((size_t)c * BHg + bh) * 4096;
    for (int idx = threadIdx.x; idx < 4096; idx += 256) {
        int t = idx >> 6, d = idx & 63;
        size_t r = ((size_t)(bl * T_SEQ + c * 64 + t)) * 1536 + hh * 64 + d;
        Qs[t * 72 + d] = qkv[r];
        Ks[t * 72 + d] = qkv[r + 512];
        Vt[d * 72 + t] = qkv[r + 1024];         // [m][t]
        Ssh[t * 72 + d] = Sp[sbase + idx];      // [m][d]
    }
    if (threadIdx.x < 64)
        Zsh[threadIdx.x] = Zp[((size_t)c * BHg + bh) * 64 + threadIdx.x];
    __syncthreads();

    if (threadIdx.x < 64) {
        float s = 0.f;
        #pragma unroll
        for (int d8 = 0; d8 < 64; d8 += 8) {
            bf16x8 qq = *(const bf16x8*)&Qs[threadIdx.x * 72 + d8];
            #pragma unroll
            for (int u = 0; u < 8; u++) s += (float)qq[u] * Zsh[d8 + u];
        }
        den2sh[threadIdx.x] = s;
    }

    int lane = threadIdx.x & 63;
    int w = threadIdx.x >> 6;
    int lrow = lane & 15, quad = lane >> 4;
    int i0 = w * 16;

    // P = Q @ K^T (row = i via reg)
    f32x4 accp[4] = {};
    #pragma unroll
    for (int k0 = 0; k0 < 64; k0 += 32) {
        bf16x8 af = *(const bf16x8*)&Qs[(i0 + lrow) * 72 + k0 + quad * 8];
        #pragma unroll
        for (int jt = 0; jt < 4; jt++) {
            bf16x8 bf = *(const bf16x8*)&Ks[(jt * 16 + lrow) * 72 + k0 + quad * 8];
            accp[jt] = __builtin_amdgcn_mfma_f32_16x16x32_bf16(af, bf, accp[jt], 0, 0, 0);
        }
    }
    #pragma unroll
    for (int r = 0; r < 4; r++) {
        int row = i0 + quad * 4 + r;
        float d1 = 0.f;
        #pragma unroll
        for (int jt = 0; jt < 4; jt++) {
            int col = jt * 16 + lrow;
            float pv = (col <= row) ? accp[jt][r] : 0.f;
            d1 += pv;
            Ps[row * 72 + col] = f2b(pv);
        }
        #pragma unroll
        for (int off = 1; off < 16; off <<= 1)
            d1 += __shfl_xor(d1, off, 64);
        if (lrow == 0) den1sh[row] = d1;
    }
    __syncthreads();

    // O = Ps @ V + Q @ S'  (swapped: first operand = m side)
    f32x4 acco[4] = {};
    #pragma unroll
    for (int k0 = 0; k0 < 64; k0 += 32) {
        bf16x8 ps = *(const bf16x8*)&Ps[(i0 + lrow) * 72 + k0 + quad * 8];
        #pragma unroll
        for (int jt = 0; jt < 4; jt++) {
            bf16x8 vf = *(const bf16x8*)&Vt[(jt * 16 + lrow) * 72 + k0 + quad * 8];
            acco[jt] = __builtin_amdgcn_mfma_f32_16x16x32_bf16(vf, ps, acco[jt], 0, 0, 0);
        }
    }
    #pragma unroll
    for (int k0 = 0; k0 < 64; k0 += 32) {
        bf16x8 qf = *(const bf16x8*)&Qs[(i0 + lrow) * 72 + k0 + quad * 8];
        #pragma unroll
        for (int jt = 0; jt < 4; jt++) {
            bf16x8 sf = *(const bf16x8*)&Ssh[(jt * 16 + lrow) * 72 + k0 + quad * 8];
            acco[jt] = __builtin_amdgcn_mfma_f32_16x16x32_bf16(sf, qf, acco[jt], 0, 0, 0);
        }
    }
    const int i = i0 + lrow;
    const float inv = 1.f / (den1sh[i] + den2sh[i] + 1e-6f);
    size_t orow = ((size_t)(bl * T_SEQ + c * 64 + i)) * 512 + hh * 64;
    #pragma unroll
    for (int jt = 0; jt < 4; jt++) {
        const int m0 = jt * 16 + quad * 4;
        union { u16 q[4]; uint2 u; } pk;
        #pragma unroll
        for (int r = 0; r < 4; r++) pk.q[r] = f2b(acco[jt][r] * inv);
        *(uint2*)&out[orow + m0] = pk.u;
    }
}

// ---------------------------------------------------------------------------
// LayerNorm (single input stream; residual pre-added in GEMM epilogue):
// out = LN(s) * g + be
// ---------------------------------------------------------------------------
__global__ __launch_bounds__(256) void ln_kernel(
    const u16* __restrict__ s_in,
    const float* __restrict__ g, const float* __restrict__ be, u16* __restrict__ out)
{
    int row = blockIdx.x * 4 + (threadIdx.x >> 6);
    int lane = threadIdx.x & 63;
    size_t base = (size_t)row * 512 + lane * 8;
    uint4 hv = *(const uint4*)&s_in[base];
    const u16* hp = (const u16*)&hv;
    float x[8]; float s = 0.f;
    #pragma unroll
    for (int i = 0; i < 8; i++) { x[i] = b2f(hp[i]); s += x[i]; }
    #pragma unroll
    for (int off = 32; off > 0; off >>= 1) s += __shfl_xor(s, off, 64);
    float m = s * (1.f / 512.f);
    float vs = 0.f;
    #pragma unroll
    for (int i = 0; i < 8; i++) { float t = x[i] - m; vs += t * t; }
    #pragma unroll
    for (int off = 32; off > 0; off >>= 1) vs += __shfl_xor(vs, off, 64);
    float rstd = rsqrtf(vs * (1.f / 512.f) + 1e-5f);
    union { u16 u[8]; uint4 v; } o;
    #pragma unroll
    for (int i = 0; i < 8; i++)
        o.u[i] = f2b((x[i] - m) * rstd * g[lane * 8 + i] + be[lane * 8 + i]);
    *(uint4*)&out[base] = o.v;
}

// ---------------------------------------------------------------------------
extern "C" void kernel_launch(void* const* d_in, const int* in_sizes, int n_in,
                              void* d_out, int out_size, void* d_ws, size_t ws_size,
                              hipStream_t stream)
{
    const int*   x  = (const int*)d_in[0];
    const float* E  = (const float*)d_in[1];
    const float* Wq = (const float*)d_in[2];
    const float* bq = (const float*)d_in[3];
    const float* Wk = (const float*)d_in[4];
    const float* bk = (const float*)d_in[5];
    const float* Wv = (const float*)d_in[6];
    const float* bv = (const float*)d_in[7];
    const float* Wo = (const float*)d_in[8];
    const float* bo = (const float*)d_in[9];
    const float* g1 = (const float*)d_in[10];
    const float* be1= (const float*)d_in[11];
    const float* W1 = (const float*)d_in[12];
    const float* b1 = (const float*)d_in[13];
    const float* W2 = (const float*)d_in[14];
    const float* b2 = (const float*)d_in[15];
    const float* g2 = (const float*)d_in[16];
    const float* be2= (const float*)d_in[17];
    const float* Wp = (const float*)d_in[18];
    const float* bp = (const float*)d_in[19];

    // --- fixed region: bf16 transposed weights + fp32 qkv bias (12.08 MiB) ---
    char* p = (char*)d_ws;
    u16* qkvT = (u16*)p; p += (size_t)2 * 1536 * 512 * 2;
    u16* woT  = (u16*)p; p += (size_t)2 * 512 * 512 * 2;
    u16* w1T  = (u16*)p; p += (size_t)2 * 2048 * 512 * 2;
    u16* w2T  = (u16*)p; p += (size_t)2 * 512 * 2048 * 2;
    u16* wpT  = (u16*)p; p += (size_t)64 * 512 * 2;
    float* bqkv = (float*)p; p += (size_t)16384;
    size_t fixed = (size_t)(p - (char*)d_ws);

    // --- adaptive batch group: Bg * 12.65 MiB ---
    const size_t perB = 12648448ULL;
    int Bg = 32;
    while (Bg > 1 && fixed + (size_t)Bg * perB > ws_size) Bg >>= 1;
    const int rows = Bg * T_SEQ;
    const int BHg = Bg * NHEADS;
    const int nbm = rows / 128;

    u16* h      = (u16*)p; p += (size_t)rows * 512 * 2;
    u16* qkvBig = (u16*)p; p += (size_t)rows * 2048 * 2;
    u16* am     = (u16*)p; p += (size_t)rows * 512 * 2;
    float* Z    = (float*)p; p += (size_t)BHg * NCHUNK * 64 * 4;
    u16* qkv = qkvBig;                        // rows x 1536 during attention
    u16* Sb  = qkvBig + (size_t)rows * 1536;  // bf16 S' tail
    u16* ff1 = qkvBig;                        // rows x 2048 during FF
    u16* o_  = qkvBig;                        // rows x 512 Wo output (h+attn)

    dim3 blk(256);

    for (int l = 0; l < 2; l++) {
        transpose_w<<<dim3(16, 16), blk, 0, stream>>>(Wq + (size_t)l * 262144, qkvT + (size_t)l * 786432,          512, 512);
        transpose_w<<<dim3(16, 16), blk, 0, stream>>>(Wk + (size_t)l * 262144, qkvT + (size_t)l * 786432 + 262144, 512, 512);
        transpose_w<<<dim3(16, 16), blk, 0, stream>>>(Wv + (size_t)l * 262144, qkvT + (size_t)l * 786432 + 524288, 512, 512);
        transpose_w<<<dim3(16, 16), blk, 0, stream>>>(Wo + (size_t)l * 262144, woT + (size_t)l * 262144,           512, 512);
        transpose_w<<<dim3(64, 16), blk, 0, stream>>>(W1 + (size_t)l * 1048576, w1T + (size_t)l * 1048576,         512, 2048);
        transpose_w<<<dim3(16, 64), blk, 0, stream>>>(W2 + (size_t)l * 1048576, w2T + (size_t)l * 1048576,         2048, 512);
    }
    transpose_w<<<dim3(2, 16), blk, 0, stream>>>(Wp, wpT, 512, 64);
    concat_bias<<<12, blk, 0, stream>>>(bq, bk, bv, bqkv);

    for (int b0 = 0; b0 < BATCH; b0 += Bg) {
        embed_kernel<<<rows * 2, blk, 0, stream>>>(x, E, h, b0);

        for (int l = 0; l < 2; l++) {
            gemm_mx<2, false><<<dim3(nbm * 12), blk, 0, stream>>>(
                h, qkvT + (size_t)l * 786432, bqkv + l * 1536, nullptr, qkv,
                rows, 1536, 512, 1024, 12, 8);
            attn_chunk_sums<<<NCHUNK * BHg, blk, 0, stream>>>(qkv, Sb, Z, BHg);
            attn_prefix<<<BHg * 16, blk, 0, stream>>>(Sb, Z, BHg);
            attn_intra<<<NCHUNK * BHg, blk, 0, stream>>>(qkv, Sb, Z, am, BHg);
            gemm_mx<0, true><<<dim3(nbm * 4), blk, 0, stream>>>(
                am, woT + (size_t)l * 262144, bo + l * 512, h, o_,
                rows, 512, 512, 0, 4, 8);
            ln_kernel<<<rows / 4, blk, 0, stream>>>(o_, g1 + l * 512, be1 + l * 512, h);
            gemm_mx<1, false><<<dim3(nbm * 16), blk, 0, stream>>>(
                h, w1T + (size_t)l * 1048576, b1 + l * 2048, nullptr, ff1,
                rows, 2048, 512, 0, 16, 8);
            gemm_mx<0, true><<<dim3(nbm * 4), blk, 0, stream>>>(
                ff1, w2T + (size_t)l * 1048576, b2 + l * 512, h, am,
                rows, 512, 2048, 0, 4, 8);
            ln_kernel<<<rows / 4, blk, 0, stream>>>(am, g2 + l * 512, be2 + l * 512, h);
        }

        gemm_sm<64, 64, 2, 2><<<dim3(1, rows / 64), blk, 0, stream>>>(
            h, wpT, bp, (float*)d_out + (size_t)b0 * T_SEQ * 64, rows, 64, 512);
    }

    (void)in_sizes; (void)n_in; (void)out_size; (void)ws_size;
}